// Round 11
// baseline (105.010 us; speedup 1.0000x reference)
//
#include <hip/hip_runtime.h>

// Nearest-prototype argmin: N=500k, K=256, D=64, fp32.
// R11: single-pass fp16 MFMA. fp16 has 11 mantissa bits -> hh-pass dot
// error std ~3.2e-3 (gap err ~4.5e-3); margin 0.03 (6.7 sigma) + exact-fp32
// fixup of flagged points (proven net, absmax=0 since R5) absorbs it.
// vs R10: MFMA volume /3 (floor 23.7 -> 7.9 us), staging split -> bare cvt,
// LDS 40 -> 23.5 KB (6 blocks/CU), A-frags 64 -> 32 VGPR. Tie logic deleted
// (exact ties have gap 0 < margin -> always fixup'd). Top-2 kept for flag.

#define DIM 64
#define NPROTO 256
#define NBLK 1536
#define SUBT 4
#define PPI 64   // points per iteration = SUBT * 16
#define MARGIN_ACC 0.015f   // = 0.03 in d2 units (d2 = -2*acc)

using f32x4 = __attribute__((ext_vector_type(4))) float;
using f16x8 = __attribute__((ext_vector_type(8))) _Float16;
using f16x4 = __attribute__((ext_vector_type(4))) _Float16;

// convert one float4 and write into a sub-tile's LDS row (8B granule wgi).
__device__ __forceinline__ void stage_one(_Float16* row, float4 v, int wgi) {
    f16x4 w0 = {(_Float16)v.x, (_Float16)v.y, (_Float16)v.z, (_Float16)v.w};
    ((f16x4*)row)[wgi] = w0;
}

__device__ __forceinline__ float4 loadx(const float* __restrict__ X, int t,
                                        int j, int srow, int spart, int n) {
    int pr = t * PPI + j * 16 + srow;
    pr = (pr < n) ? pr : (n - 1);   // OOB rows clamp; store is guarded
    return *(const float4*)(X + (size_t)pr * DIM + spart * 4);
}

__attribute__((amdgpu_waves_per_eu(4, 8)))
__global__ void __launch_bounds__(256)
argmin_mfma_kernel(const float* __restrict__ X,
                   const float* __restrict__ mus,
                   int* __restrict__ out,
                   unsigned* __restrict__ ws_count,
                   int* __restrict__ ws_list,
                   int use_list, int n) {
    __shared__ __align__(16) _Float16 s_x[2][SUBT][16][64];  // 16 KB
    __shared__ float s_musq[NPROTO];   // holds -0.5*musq
    __shared__ float s_cb[2][SUBT][4][16];
    __shared__ float s_cb2[2][SUBT][4][16];
    __shared__ int   s_ck[2][SUBT][4][16];

    const int tid = threadIdx.x;
    const int w  = tid >> 6;   // wave 0..3 -> protos [w*64, w*64+64)
    const int l  = tid & 63;
    const int lp = l & 15;     // A-row / B-col lane index
    const int lg = l >> 4;     // k-group

    // ---- per-block -musq/2 (fp32, 4-stripe order, absmax=0 heritage) ----
    {
        const float4* m4 = (const float4*)(mus + tid * DIM);
        float a0 = 0.f, a1 = 0.f, a2 = 0.f, a3 = 0.f;
#pragma unroll
        for (int q = 0; q < 16; ++q) {
            float4 v = m4[q];
            a0 = fmaf(v.x, v.x, a0); a1 = fmaf(v.y, v.y, a1);
            a2 = fmaf(v.z, v.z, a2); a3 = fmaf(v.w, v.w, a3);
        }
        s_musq[tid] = -0.5f * ((a0 + a1) + (a2 + a3));
    }

    // ---- per-wave persistent A-frags: 64 protos x K64, fp16 hi only ----
    f16x8 amu[4][2];
#pragma unroll
    for (int t = 0; t < 4; ++t) {
        const int p = w * 64 + t * 16 + lp;
#pragma unroll
        for (int h = 0; h < 2; ++h) {
            const float* src = mus + (size_t)p * DIM + h * 32 + lg * 8;
            const float4 va = *(const float4*)src;
            const float4 vb = *(const float4*)(src + 4);
            f16x8 m0 = {(_Float16)va.x, (_Float16)va.y, (_Float16)va.z,
                        (_Float16)va.w, (_Float16)vb.x, (_Float16)vb.y,
                        (_Float16)vb.z, (_Float16)vb.w};
            amu[t][h] = m0;
        }
    }

    // ---- 64-point tile range for this block ----
    const int ntiles = (n + PPI - 1) / PPI;   // 7813
    const int q = ntiles / NBLK, rr = ntiles % NBLK;
    const int bid = blockIdx.x;
    const int t0  = bid * q + (bid < rr ? bid : rr);
    const int cnt = q + (bid < rr ? 1 : 0);

    const int srow = tid >> 4, spart = tid & 15;
    const int wgi = spart ^ ((srow & 7) << 1);  // swizzled 8B-granule index

    // prologue: load + stage tile t0 into buf 0 (all 4 sub-tiles)
    float4 xn0 = loadx(X, t0, 0, srow, spart, n);
    float4 xn1 = loadx(X, t0, 1, srow, spart, n);
    float4 xn2 = loadx(X, t0, 2, srow, spart, n);
    float4 xn3 = loadx(X, t0, 3, srow, spart, n);
    stage_one(&s_x[0][0][srow][0], xn0, wgi);
    stage_one(&s_x[0][1][srow][0], xn1, wgi);
    stage_one(&s_x[0][2][srow][0], xn2, wgi);
    stage_one(&s_x[0][3][srow][0], xn3, wgi);
    __syncthreads();  // publishes s_musq + tile 0

    // C-seed fragments: mh[t][r] = -0.5*musq for this lane's 16 slots
    const int kbase = w * 64 + lg * 4;
    f32x4 mh[4];
#pragma unroll
    for (int t = 0; t < 4; ++t)
#pragma unroll
        for (int r = 0; r < 4; ++r)
            mh[t][r] = s_musq[kbase + t * 16 + r];

    for (int it = 0; it < cnt; ++it) {
        const int tile = t0 + it;
        const int par = it & 1;
        const bool more = (it + 1 < cnt);

        // issue next tile's loads at iteration TOP; consumed by staging at
        // iteration END -> issue->use spans 32 MFMAs + 4 epilogues
        if (more) {
            xn0 = loadx(X, tile + 1, 0, srow, spart, n);
            xn1 = loadx(X, tile + 1, 1, srow, spart, n);
            xn2 = loadx(X, tile + 1, 2, srow, spart, n);
            xn3 = loadx(X, tile + 1, 3, srow, spart, n);
        }

#pragma unroll
        for (int j = 0; j < SUBT; ++j) {
            // B-frags from s_x[par][j] (swizzled 16B reads)
            f16x8 bx[2];
#pragma unroll
            for (int h = 0; h < 2; ++h)
                bx[h] = ((const f16x8*)&s_x[par][j][lp][0])
                            [(h * 4 + lg) ^ (lp & 7)];

            // acc = hh_dot - musq/2 : h=0 seeds with mh, h=1 accumulates
            f32x4 acc[4];
#pragma unroll
            for (int t = 0; t < 4; ++t)
                acc[t] = __builtin_amdgcn_mfma_f32_16x16x32_f16(
                    amu[t][0], bx[0], mh[t], 0, 0, 0);
#pragma unroll
            for (int t = 0; t < 4; ++t)
                acc[t] = __builtin_amdgcn_mfma_f32_16x16x32_f16(
                    amu[t][1], bx[1], acc[t], 0, 0, 0);

            // ---- tree top-2 + argmax over 16 slots (no tie logic: exact
            // ties have gap 0 < margin -> always resolved by exact fixup) ----
            float m1[8], m2[8];
            int   ka[8];
#pragma unroll
            for (int p = 0; p < 8; ++p) {
                const int t = p >> 1, rbase = (p & 1) * 2;
                const float da = acc[t][rbase], db = acc[t][rbase + 1];
                const bool gt = db > da;
                m1[p] = fmaxf(da, db);
                m2[p] = fminf(da, db);
                ka[p] = kbase + t * 16 + (gt ? rbase + 1 : rbase);
            }
#pragma unroll
            for (int lvl = 0; lvl < 3; ++lvl) {
                const int step = 1 << lvl;
#pragma unroll
                for (int p = 0; p < 8; p += 2 * step) {
                    const int pb = p + step;
                    const bool gt = m1[pb] > m1[p];
                    const float lo = fminf(m1[p], m1[pb]);
                    m1[p] = fmaxf(m1[p], m1[pb]);
                    ka[p] = gt ? ka[pb] : ka[p];
                    m2[p] = fmaxf(fmaxf(lo, m2[p]), m2[pb]);  // v_max3
                }
            }
            float b1 = m1[0], b2 = m2[0];
            int k1 = ka[0];

            // cross-lane over lg (lanes with same lp share a point)
#pragma unroll
            for (int m = 16; m <= 32; m <<= 1) {
                const float ob1 = __shfl_xor(b1, m);
                const float ob2 = __shfl_xor(b2, m);
                const int   ok1 = __shfl_xor(k1, m);
                const bool take = ob1 > b1;
                b2 = fmaxf(fmaxf(fminf(b1, ob1), b2), ob2);
                b1 = fmaxf(b1, ob1);
                k1 = take ? ok1 : k1;
            }
            if (lg == 0) {
                s_cb[par][j][w][lp] = b1;
                s_cb2[par][j][w][lp] = b2;
                s_ck[par][j][w][lp] = k1;
            }
        }

        // cooperative stage of next tile into the other buffer
        if (more) {
            stage_one(&s_x[par ^ 1][0][srow][0], xn0, wgi);
            stage_one(&s_x[par ^ 1][1][srow][0], xn1, wgi);
            stage_one(&s_x[par ^ 1][2][srow][0], xn2, wgi);
            stage_one(&s_x[par ^ 1][3][srow][0], xn3, wgi);
        }

        __syncthreads();

        // merge 4 waves for all 64 points (wave 0, one lane per point)
        if (tid < PPI) {
            const int j = tid >> 4, c = tid & 15;
            float f1 = s_cb[par][j][0][c], f2 = s_cb2[par][j][0][c];
            int fk = s_ck[par][j][0][c];
#pragma unroll
            for (int ww = 1; ww < 4; ++ww) {
                const float ob1 = s_cb[par][j][ww][c];
                const float ob2 = s_cb2[par][j][ww][c];
                const int   ok1 = s_ck[par][j][ww][c];
                const bool take = ob1 > f1;
                f2 = fmaxf(fmaxf(fminf(f1, ob1), f2), ob2);
                f1 = fmaxf(f1, ob1);
                fk = take ? ok1 : fk;
            }
            const int i = tile * PPI + tid;
            if (i < n) {
                const bool close = (f1 - f2) < MARGIN_ACC;
                if (use_list) {
                    out[i] = fk;  // clean index; flagged points go to the list
                    if (close) {
                        const unsigned idx = atomicAdd(ws_count, 1u);
                        ws_list[idx] = i;  // capacity >= n guaranteed by host
                    }
                } else {
                    out[i] = (int)((unsigned)fk | (close ? 0x80000000u : 0u));
                }
            }
        }
    }
}

// Exact-fp32 wave-cooperative recompute of one point (R2-proven order).
__device__ __forceinline__ int recompute_point(const float* __restrict__ X,
                                               const float* __restrict__ mus,
                                               int pt, int l) {
    const float4* xr = (const float4*)(X + (size_t)pt * DIM);
    float4 xv[16];
    float xa0 = 0.f, xa1 = 0.f, xa2 = 0.f, xa3 = 0.f;
#pragma unroll
    for (int qq = 0; qq < 16; ++qq) {
        xv[qq] = xr[qq];
        xa0 = fmaf(xv[qq].x, xv[qq].x, xa0);
        xa1 = fmaf(xv[qq].y, xv[qq].y, xa1);
        xa2 = fmaf(xv[qq].z, xv[qq].z, xa2);
        xa3 = fmaf(xv[qq].w, xv[qq].w, xa3);
    }
    const float xsq = (xa0 + xa1) + (xa2 + xa3);
    float b1 = 3.4e38f; int k1 = 0;
#pragma unroll
    for (int e = 0; e < 4; ++e) {
        const int p = l * 4 + e;
        const float4* mr = (const float4*)(mus + (size_t)p * DIM);
        float d0 = 0.f, d1 = 0.f, d2a = 0.f, d3 = 0.f;
        float q0 = 0.f, q1 = 0.f, q2 = 0.f, q3 = 0.f;
#pragma unroll
        for (int qq = 0; qq < 16; ++qq) {
            const float4 mv = mr[qq];
            d0 = fmaf(mv.x, xv[qq].x, d0);
            d1 = fmaf(mv.y, xv[qq].y, d1);
            d2a = fmaf(mv.z, xv[qq].z, d2a);
            d3 = fmaf(mv.w, xv[qq].w, d3);
            q0 = fmaf(mv.x, mv.x, q0);
            q1 = fmaf(mv.y, mv.y, q1);
            q2 = fmaf(mv.z, mv.z, q2);
            q3 = fmaf(mv.w, mv.w, q3);
        }
        const float dot = (d0 + d1) + (d2a + d3);
        const float msq = (q0 + q1) + (q2 + q3);
        const float dd = (xsq - 2.0f * dot) + msq;
        if (dd < b1) { b1 = dd; k1 = p; }
    }
#pragma unroll
    for (int mm = 1; mm < 64; mm <<= 1) {
        const float ob = __shfl_xor(b1, mm);
        const int ok = __shfl_xor(k1, mm);
        if (ob < b1 || (ob == b1 && ok < k1)) { b1 = ob; k1 = ok; }
    }
    return k1;
}

// List-driven fixup: one wave per flagged point, grid-stride over the list.
__global__ void __launch_bounds__(256)
fixup_list_kernel(const float* __restrict__ X, const float* __restrict__ mus,
                  const unsigned* __restrict__ ws_count,
                  const int* __restrict__ ws_list, int* __restrict__ out) {
    const int gw = (int)((blockIdx.x * blockDim.x + threadIdx.x) >> 6);
    const int l  = threadIdx.x & 63;
    const int NW = (int)((gridDim.x * blockDim.x) >> 6);
    const int nf = (int)*ws_count;
    for (int j = gw; j < nf; j += NW) {
        const int pt = ws_list[j];
        const int k1 = recompute_point(X, mus, pt, l);
        if (l == 0) out[pt] = k1;
    }
}

// Fallback scan fixup (flag bit 31 in out), used if ws too small.
__global__ void __launch_bounds__(256)
fixup_scan_kernel(const float* __restrict__ X, const float* __restrict__ mus,
                  int* __restrict__ out, int n) {
    const int gw = (int)((blockIdx.x * blockDim.x + threadIdx.x) >> 6);
    const int l  = threadIdx.x & 63;
    const int NW = (int)((gridDim.x * blockDim.x) >> 6);
    const int chunk = (n + NW - 1) / NW;
    const int base = gw * chunk;
    const int end  = (base + chunk < n) ? (base + chunk) : n;
    for (int s = base; s < end; s += 64) {
        const int i = s + l;
        const int v = (i < end) ? out[i] : 0;
        const bool fl = (i < end) && ((unsigned)v & 0x80000000u);
        unsigned long long m = __ballot(fl);
        while (m) {
            const int src = (int)__ffsll((unsigned long long)m) - 1;
            m &= m - 1;
            const int pt = __shfl(i, src);
            const int k1 = recompute_point(X, mus, pt, l);
            if (l == 0) out[pt] = k1;
        }
    }
}

extern "C" void kernel_launch(void* const* d_in, const int* in_sizes, int n_in,
                              void* d_out, int out_size, void* d_ws, size_t ws_size,
                              hipStream_t stream) {
    const float* X = (const float*)d_in[0];
    const float* mus = (const float*)d_in[1];
    int* out = (int*)d_out;
    const int n = in_sizes[0] / DIM;  // 500000

    unsigned* ws_count = (unsigned*)d_ws;
    int* ws_list = (int*)((char*)d_ws + 16);
    const int use_list = (ws_size >= 16 + (size_t)n * 4) ? 1 : 0;

    if (use_list) {
        hipMemsetAsync(d_ws, 0, 16, stream);  // reset append counter
    }

    argmin_mfma_kernel<<<NBLK, 256, 0, stream>>>(X, mus, out, ws_count,
                                                 ws_list, use_list, n);
    if (use_list) {
        fixup_list_kernel<<<1024, 256, 0, stream>>>(X, mus, ws_count, ws_list,
                                                    out);
    } else {
        fixup_scan_kernel<<<512, 256, 0, stream>>>(X, mus, out, n);
    }
}